// Round 6
// baseline (1213.067 us; speedup 1.0000x reference)
//
#include <hip/hip_runtime.h>

#define N_TOK 8192
#define DIM   1024
#define HID   4096
#define OUTD  1024
#define NE    8
#define CAPE  4096

typedef _Float16 f16;
typedef f16  f16x8 __attribute__((ext_vector_type(8)));
typedef f16  f16x4 __attribute__((ext_vector_type(4)));
typedef float f32x4 __attribute__((ext_vector_type(4)));

__device__ __forceinline__ void gload16(const void* g, void* l) {
  __builtin_amdgcn_global_load_lds(
      (const __attribute__((address_space(1))) void*)g,
      (__attribute__((address_space(3))) void*)l, 16, 0, 0);
}

// ---------------- zero control block ----------------
__global__ void zero_ctrl(int* counts) {
  if (threadIdx.x < NE) counts[threadIdx.x] = 0;
}

// ---------------- zero the output buffer (poisoned 0xAA by harness) ------
__global__ __launch_bounds__(256) void zero_out(float4* __restrict__ p) {
  p[(size_t)blockIdx.x * 256 + threadIdx.x] = float4{0.f, 0.f, 0.f, 0.f};
}

// ---------------- transpose + fp32->f16 convert (one expert group) -------
// in: (E, R, C) fp32, experts g0..g0+G-1 ; out: (G, C, R) f16
__global__ __launch_bounds__(256) void transpose_cvt(
    const float* __restrict__ in, f16* __restrict__ out, int R, int C, int g0) {
  __shared__ float tile[32][33];
  const int ez = blockIdx.z;
  const int r0 = blockIdx.y * 32;
  const int c0 = blockIdx.x * 32;
  const float* ip = in  + (size_t)(g0 + ez) * R * C;
  f16*         op = out + (size_t)ez * R * C;
  const int tx = threadIdx.x;   // 0..31
  const int ty = threadIdx.y;   // 0..7
#pragma unroll
  for (int k = 0; k < 4; ++k) {
    int r = ty + k * 8;
    tile[r][tx] = ip[(size_t)(r0 + r) * C + c0 + tx];
  }
  __syncthreads();
#pragma unroll
  for (int k = 0; k < 4; ++k) {
    int r = ty + k * 8;
    op[(size_t)(c0 + r) * R + r0 + tx] = (f16)tile[tx][r];
  }
}

// ---------------- gating: logits, softmax, top-2, stats ----------------
__global__ __launch_bounds__(256) void gate_kernel(
    const float* __restrict__ x, const float* __restrict__ gW,
    const float* __restrict__ gb, int* __restrict__ counts,
    int* __restrict__ tk_e, int* __restrict__ tk_pos, float* __restrict__ tk_w,
    float* __restrict__ blockImp, float* __restrict__ blockRw) {
  const int tid  = threadIdx.x;
  const int wave = tid >> 6;
  const int lane = tid & 63;
  const int t    = blockIdx.x * 4 + wave;

  float acc[NE];
#pragma unroll
  for (int e = 0; e < NE; ++e) acc[e] = 0.f;

  const float* xr = x + (size_t)t * DIM;
  for (int d = lane; d < DIM; d += 64) {
    float xv = xr[d];
#pragma unroll
    for (int e = 0; e < NE; ++e) acc[e] += xv * gW[e * DIM + d];
  }
#pragma unroll
  for (int off = 32; off; off >>= 1) {
#pragma unroll
    for (int e = 0; e < NE; ++e) acc[e] += __shfl_xor(acc[e], off);
  }
  float p[NE];
  float mx = -1e30f;
#pragma unroll
  for (int e = 0; e < NE; ++e) { p[e] = acc[e] + gb[e]; mx = fmaxf(mx, p[e]); }
  float s = 0.f;
#pragma unroll
  for (int e = 0; e < NE; ++e) { p[e] = expf(p[e] - mx); s += p[e]; }
  float inv = 1.f / s;
#pragma unroll
  for (int e = 0; e < NE; ++e) p[e] *= inv;

  // top-2, first-index-wins on ties (strict >)
  int e0 = 0;
#pragma unroll
  for (int e = 1; e < NE; ++e) if (p[e] > p[e0]) e0 = e;
  int e1 = (e0 == 0) ? 1 : 0;
#pragma unroll
  for (int e = 0; e < NE; ++e) if (e != e0 && p[e] > p[e1]) e1 = e;

  __shared__ float simp[4][NE];
  __shared__ float srw[4][NE];
  if (lane == 0) {
    int p0 = atomicAdd(&counts[e0], 1);
    int p1 = atomicAdd(&counts[e1], 1);
    tk_e[t * 2]     = e0;  tk_e[t * 2 + 1]   = e1;
    tk_pos[t * 2]   = p0;  tk_pos[t * 2 + 1] = p1;
    tk_w[t * 2]     = p[e0]; tk_w[t * 2 + 1] = p[e1];
#pragma unroll
    for (int e = 0; e < NE; ++e) {
      simp[wave][e] = p[e];
      srw[wave][e]  = (e == e0) ? p[e0] : ((e == e1) ? p[e1] : 0.f);
    }
  }
  __syncthreads();
  if (tid < NE) {
    float si = 0.f, sr = 0.f;
#pragma unroll
    for (int w = 0; w < 4; ++w) { si += simp[w][tid]; sr += srw[w][tid]; }
    blockImp[blockIdx.x * NE + tid] = si;
    blockRw[blockIdx.x * NE + tid]  = sr;
  }
}

// ------- gather x rows into expert-group slots (f16) + slot maps --------
// writes only assignments routed to experts [g0, g0+G); Xg indexed by e-g0
__global__ __launch_bounds__(256) void gather_x(
    const float* __restrict__ x, const int* __restrict__ tk_e,
    const int* __restrict__ tk_pos, const float* __restrict__ tk_w,
    f16* __restrict__ Xg, int* __restrict__ slot_tok,
    float* __restrict__ slot_w, int g0, int G) {
  const int i   = blockIdx.x;        // 0 .. N*K-1
  const int e   = tk_e[i];
  if (e < g0 || e >= g0 + G) return;
  const int pos = tk_pos[i];
  if (pos >= CAPE) return;
  const int t = i >> 1;
  if (threadIdx.x == 0) {
    slot_tok[e * CAPE + pos] = t;    // absolute expert index
    slot_w[e * CAPE + pos]   = tk_w[i];
  }
  const float4* src = (const float4*)(x + (size_t)t * DIM);
  f16* dst = Xg + ((size_t)((e - g0) * CAPE + pos)) * DIM;
  const int c = threadIdx.x;         // 0..255, 4 floats each
  float4 v = src[c];
  f16x4 h;
  h.x = (f16)v.x; h.y = (f16)v.y; h.z = (f16)v.z; h.w = (f16)v.w;
  *(f16x4*)(dst + c * 4) = h;
}

// ---------------- GEMM1: Hb = relu(Xg @ W1 + b1), f16 out ----------------
// Xg: (G,CAPE,DIM) f16 ; W1t: (G,HID,DIM) f16 ; Hb: (G,CAPE,HID) f16
__global__ __launch_bounds__(256) void gemm1_kernel(
    const f16* __restrict__ Xg, const f16* __restrict__ W1t,
    const float* __restrict__ b1, f16* __restrict__ Hb,
    const int* __restrict__ counts, int g0) {
  const int ez  = blockIdx.z;
  const int e   = g0 + ez;
  int cnt = counts[e]; if (cnt > CAPE) cnt = CAPE;
  const int brow = blockIdx.y;
  const int bcol = blockIdx.x;
  if (brow * 128 >= cnt) return;

  __shared__ f16 As[128 * 32];
  __shared__ f16 Bs[128 * 32];

  const int tid  = threadIdx.x;
  const int wave = tid >> 6, lane = tid & 63;
  const int wr = wave >> 1, wc = wave & 1;
  const int srow = tid >> 2;
  const int scol = (tid & 3) * 8;

  const f16* Ab = Xg  + ((size_t)ez * CAPE + brow * 128) * DIM;
  const f16* Bb = W1t + ((size_t)ez * HID  + bcol * 128) * DIM;

  f32x4 acc[4][4];
#pragma unroll
  for (int i = 0; i < 4; ++i)
#pragma unroll
    for (int j = 0; j < 4; ++j) acc[i][j] = (f32x4){0.f, 0.f, 0.f, 0.f};

  const int fr = lane & 15, fk = (lane >> 4) * 8;

  for (int kt = 0; kt < DIM / 32; ++kt) {
    const f16* Ak = Ab + kt * 32;
    const f16* Bk = Bb + kt * 32;
    gload16(Ak + (size_t)srow * DIM + scol,        As + wave * 512);
    gload16(Ak + (size_t)(srow + 64) * DIM + scol, As + 2048 + wave * 512);
    gload16(Bk + (size_t)srow * DIM + scol,        Bs + wave * 512);
    gload16(Bk + (size_t)(srow + 64) * DIM + scol, Bs + 2048 + wave * 512);
    __syncthreads();
    f16x8 af[4], bf[4];
#pragma unroll
    for (int i = 0; i < 4; ++i)
      af[i] = *(const f16x8*)&As[(wr * 64 + i * 16 + fr) * 32 + fk];
#pragma unroll
    for (int j = 0; j < 4; ++j)
      bf[j] = *(const f16x8*)&Bs[(wc * 64 + j * 16 + fr) * 32 + fk];
#pragma unroll
    for (int i = 0; i < 4; ++i)
#pragma unroll
      for (int j = 0; j < 4; ++j)
        acc[i][j] = __builtin_amdgcn_mfma_f32_16x16x32_f16(af[i], bf[j], acc[i][j], 0, 0, 0);
    __syncthreads();
  }

  const int rbase = (lane >> 4) * 4;
  const int crow0 = brow * 128 + wr * 64;
  const int ccol0 = bcol * 128 + wc * 64;
  f16* Cb = Hb + (size_t)ez * CAPE * HID;
#pragma unroll
  for (int j = 0; j < 4; ++j) {
    int col = ccol0 + j * 16 + fr;
    float bias = b1[e * HID + col];
#pragma unroll
    for (int i = 0; i < 4; ++i) {
#pragma unroll
      for (int r = 0; r < 4; ++r) {
        int row = crow0 + i * 16 + rbase + r;
        float v = acc[i][j][r] + bias;
        Cb[(size_t)row * HID + col] = (f16)(v > 0.f ? v : 0.f);
      }
    }
  }
}

// ---------------- GEMM2: out[tok] += w * (Hb @ W2 + b2) ----------------
// Hb: (G,CAPE,HID) f16 ; W2t: (G,OUTD,HID) f16 ; scatter-add into out fp32
__global__ __launch_bounds__(256) void gemm2_kernel(
    const f16* __restrict__ Hb, const f16* __restrict__ W2t,
    const float* __restrict__ b2, float* __restrict__ out,
    const int* __restrict__ slot_tok, const float* __restrict__ slot_w,
    const int* __restrict__ counts, int g0) {
  const int ez  = blockIdx.z;
  const int e   = g0 + ez;
  int cnt = counts[e]; if (cnt > CAPE) cnt = CAPE;
  const int brow = blockIdx.y;
  const int bcol = blockIdx.x;
  if (brow * 128 >= cnt) return;

  __shared__ f16 As[128 * 32];
  __shared__ f16 Bs[128 * 32];

  const int tid  = threadIdx.x;
  const int wave = tid >> 6, lane = tid & 63;
  const int wr = wave >> 1, wc = wave & 1;
  const int srow = tid >> 2;
  const int scol = (tid & 3) * 8;

  const f16* Ab = Hb  + ((size_t)ez * CAPE + brow * 128) * HID;
  const f16* Bb = W2t + ((size_t)ez * OUTD + bcol * 128) * HID;

  f32x4 acc[4][4];
#pragma unroll
  for (int i = 0; i < 4; ++i)
#pragma unroll
    for (int j = 0; j < 4; ++j) acc[i][j] = (f32x4){0.f, 0.f, 0.f, 0.f};

  const int fr = lane & 15, fk = (lane >> 4) * 8;

  for (int kt = 0; kt < HID / 32; ++kt) {
    const f16* Ak = Ab + kt * 32;
    const f16* Bk = Bb + kt * 32;
    gload16(Ak + (size_t)srow * HID + scol,        As + wave * 512);
    gload16(Ak + (size_t)(srow + 64) * HID + scol, As + 2048 + wave * 512);
    gload16(Bk + (size_t)srow * HID + scol,        Bs + wave * 512);
    gload16(Bk + (size_t)(srow + 64) * HID + scol, Bs + 2048 + wave * 512);
    __syncthreads();
    f16x8 af[4], bf[4];
#pragma unroll
    for (int i = 0; i < 4; ++i)
      af[i] = *(const f16x8*)&As[(wr * 64 + i * 16 + fr) * 32 + fk];
#pragma unroll
    for (int j = 0; j < 4; ++j)
      bf[j] = *(const f16x8*)&Bs[(wc * 64 + j * 16 + fr) * 32 + fk];
#pragma unroll
    for (int i = 0; i < 4; ++i)
#pragma unroll
      for (int j = 0; j < 4; ++j)
        acc[i][j] = __builtin_amdgcn_mfma_f32_16x16x32_f16(af[i], bf[j], acc[i][j], 0, 0, 0);
    __syncthreads();
  }

  const int rbase = (lane >> 4) * 4;
  const int crow0 = brow * 128 + wr * 64;
  const int ccol0 = bcol * 128 + wc * 64;

  // per-lane row -> token/weight (same for all j)
  int   tok[4][4];
  float twt[4][4];
#pragma unroll
  for (int i = 0; i < 4; ++i) {
#pragma unroll
    for (int r = 0; r < 4; ++r) {
      int row = crow0 + i * 16 + rbase + r;
      if (row < cnt) {
        tok[i][r] = slot_tok[(size_t)e * CAPE + row];
        twt[i][r] = slot_w[(size_t)e * CAPE + row];
      } else {
        tok[i][r] = -1;
        twt[i][r] = 0.f;
      }
    }
  }

#pragma unroll
  for (int j = 0; j < 4; ++j) {
    int col = ccol0 + j * 16 + fr;
    float bias = b2[e * OUTD + col];
#pragma unroll
    for (int i = 0; i < 4; ++i) {
#pragma unroll
      for (int r = 0; r < 4; ++r) {
        if (tok[i][r] >= 0) {
          float v = twt[i][r] * (acc[i][j][r] + bias);
          atomicAdd(&out[(size_t)tok[i][r] * OUTD + col], v);
        }
      }
    }
  }
}

// ---------------- aux loss ----------------
__global__ void aux_kernel(const float* __restrict__ blockImp,
                           const float* __restrict__ blockRw,
                           const int* __restrict__ counts,
                           float* __restrict__ out_aux) {
  const int lane = threadIdx.x;     // 64 threads
  const int e   = lane >> 3;        // 8 lanes per expert
  const int idx = lane & 7;
  double imp = 0.0, rw = 0.0;
  for (int b = idx; b < N_TOK / 4; b += 8) {
    imp += (double)blockImp[b * NE + e];
    rw  += (double)blockRw[b * NE + e];
  }
#pragma unroll
  for (int off = 1; off < 8; off <<= 1) {
    imp += __shfl_xor(imp, off);
    rw  += __shfl_xor(rw, off);
  }
  __shared__ double simp[NE], srw[NE];
  if (idx == 0) { simp[e] = imp; srw[e] = rw; }
  __syncthreads();
  if (lane == 0) {
    double mean = 0.0;
    for (int i = 0; i < NE; ++i) mean += simp[i];
    mean /= NE;
    double var = 0.0;
    for (int i = 0; i < NE; ++i) { double d = simp[i] - mean; var += d * d; }
    var /= (NE - 1);
    double il = var / (NE * NE);
    double lb = 0.0;
    for (int i = 0; i < NE; ++i)
      lb += ((double)counts[i] / N_TOK) * (srw[i] / N_TOK);
    lb *= NE;
    out_aux[0] = (float)(il + lb);
  }
}

extern "C" void kernel_launch(void* const* d_in, const int* in_sizes, int n_in,
                              void* d_out, int out_size, void* d_ws, size_t ws_size,
                              hipStream_t stream) {
  const float* x   = (const float*)d_in[0];
  const float* gW  = (const float*)d_in[1];
  const float* gb  = (const float*)d_in[2];
  const float* W1  = (const float*)d_in[3];
  const float* b1  = (const float*)d_in[4];
  const float* W2  = (const float*)d_in[5];
  const float* b2  = (const float*)d_in[6];
  float* out = (float*)d_out;

  char* ws = (char*)d_ws;
  size_t off = 0;
  // small control arrays first (~0.6 MB)
  int* counts   = (int*)(ws + off); off += 256;
  int* tk_e     = (int*)(ws + off); off += (size_t)N_TOK * 2 * 4;
  int* tk_pos   = (int*)(ws + off); off += (size_t)N_TOK * 2 * 4;
  float* tk_w   = (float*)(ws + off); off += (size_t)N_TOK * 2 * 4;
  int* slot_tok = (int*)(ws + off); off += (size_t)NE * CAPE * 4;
  float* slot_w = (float*)(ws + off); off += (size_t)NE * CAPE * 4;
  float* blockImp = (float*)(ws + off); off += (size_t)(N_TOK / 4) * NE * 4;
  float* blockRw  = (float*)(ws + off); off += (size_t)(N_TOK / 4) * NE * 4;
  off = (off + 255) & ~(size_t)255;

  // per-expert byte sizes of the group-resident buffers
  const size_t w1t_pe = (size_t)HID  * DIM * 2;   // 8 MB
  const size_t w2t_pe = (size_t)OUTD * HID * 2;   // 8 MB
  const size_t xg_pe  = (size_t)CAPE * DIM * 2;   // 8 MB
  const size_t hb_pe  = (size_t)CAPE * HID * 2;   // 32 MB
  const size_t per_e  = w1t_pe + w2t_pe + xg_pe + hb_pe;  // 56 MB

  // largest group size G (power of two) that fits
  int G = 1;
  for (int g = NE; g >= 1; g >>= 1) {
    if (off + (size_t)g * per_e <= ws_size) { G = g; break; }
  }

  f16* W1t = (f16*)(ws + off); off += (size_t)G * w1t_pe;
  f16* W2t = (f16*)(ws + off); off += (size_t)G * w2t_pe;
  f16* Xg  = (f16*)(ws + off); off += (size_t)G * xg_pe;
  f16* Hb  = (f16*)(ws + off);

  zero_ctrl<<<1, 64, 0, stream>>>(counts);
  zero_out<<<(N_TOK * OUTD / 4) / 256, 256, 0, stream>>>((float4*)out);

  gate_kernel<<<N_TOK / 4, 256, 0, stream>>>(x, gW, gb, counts, tk_e, tk_pos, tk_w,
                                             blockImp, blockRw);

  for (int g0 = 0; g0 < NE; g0 += G) {
    transpose_cvt<<<dim3(HID / 32, DIM / 32, G), dim3(32, 8), 0, stream>>>(
        W1, W1t, DIM, HID, g0);
    transpose_cvt<<<dim3(OUTD / 32, HID / 32, G), dim3(32, 8), 0, stream>>>(
        W2, W2t, HID, OUTD, g0);
    gather_x<<<N_TOK * 2, 256, 0, stream>>>(x, tk_e, tk_pos, tk_w, Xg,
                                            slot_tok, slot_w, g0, G);
    gemm1_kernel<<<dim3(HID / 128, CAPE / 128, G), 256, 0, stream>>>(
        Xg, W1t, b1, Hb, counts, g0);
    gemm2_kernel<<<dim3(OUTD / 128, CAPE / 128, G), 256, 0, stream>>>(
        Hb, W2t, b2, out, slot_tok, slot_w, counts, g0);
  }

  aux_kernel<<<1, 64, 0, stream>>>(blockImp, blockRw, counts, out + (size_t)N_TOK * OUTD);
}

// Round 8
// 1065.927 us; speedup vs baseline: 1.1380x; 1.1380x over previous
//
#include <hip/hip_runtime.h>

#define N_TOK 8192
#define DIM   1024
#define HID   4096
#define OUTD  1024
#define NE    8
#define CAPE  4096

typedef _Float16 f16;
typedef f16  f16x8 __attribute__((ext_vector_type(8)));
typedef f16  f16x4 __attribute__((ext_vector_type(4)));
typedef float f32x4 __attribute__((ext_vector_type(4)));

__device__ __forceinline__ void gload16(const void* g, void* l) {
  __builtin_amdgcn_global_load_lds(
      (const __attribute__((address_space(1))) void*)g,
      (__attribute__((address_space(3))) void*)l, 16, 0, 0);
}

// ---------------- zero control block ----------------
__global__ void zero_ctrl(int* counts) {
  if (threadIdx.x < NE) counts[threadIdx.x] = 0;
}

// ------------- transpose + fp32->f16 convert, 64x64 tiles ---------------
// in: (E, R, C) fp32, experts g0..g0+G-1 ; out: (G, C, R) f16
// block 256 = (x64, y4); wave writes 128B contiguous f16.
__global__ __launch_bounds__(256) void transpose_cvt(
    const float* __restrict__ in, f16* __restrict__ out, int R, int C, int g0) {
  __shared__ float tile[64][65];
  const int ez = blockIdx.z;
  const int r0 = blockIdx.y * 64;
  const int c0 = blockIdx.x * 64;
  const float* ip = in  + (size_t)(g0 + ez) * R * C;
  f16*         op = out + (size_t)ez * R * C;
  const int tx = threadIdx.x;   // 0..63
  const int ty = threadIdx.y;   // 0..3
#pragma unroll
  for (int k = 0; k < 16; ++k) {
    int r = ty + k * 4;
    tile[r][tx] = ip[(size_t)(r0 + r) * C + c0 + tx];
  }
  __syncthreads();
#pragma unroll
  for (int k = 0; k < 16; ++k) {
    int cc = ty + k * 4;
    // LDS read tile[tx][cc]: bank = (tx*65+cc)%32 = (tx+cc)%32 -> 2-way, free
    op[(size_t)(c0 + cc) * R + r0 + tx] = (f16)tile[tx][cc];
  }
}

// ---------------- gating: logits, softmax, top-2, stats ----------------
__global__ __launch_bounds__(256) void gate_kernel(
    const float* __restrict__ x, const float* __restrict__ gW,
    const float* __restrict__ gb, int* __restrict__ counts,
    int* __restrict__ tk_e, int* __restrict__ tk_pos, float* __restrict__ tk_w,
    float* __restrict__ blockImp, float* __restrict__ blockRw) {
  const int tid  = threadIdx.x;
  const int wave = tid >> 6;
  const int lane = tid & 63;
  const int t    = blockIdx.x * 4 + wave;

  float acc[NE];
#pragma unroll
  for (int e = 0; e < NE; ++e) acc[e] = 0.f;

  const float* xr = x + (size_t)t * DIM;
  for (int d = lane; d < DIM; d += 64) {
    float xv = xr[d];
#pragma unroll
    for (int e = 0; e < NE; ++e) acc[e] += xv * gW[e * DIM + d];
  }
#pragma unroll
  for (int off = 32; off; off >>= 1) {
#pragma unroll
    for (int e = 0; e < NE; ++e) acc[e] += __shfl_xor(acc[e], off);
  }
  float p[NE];
  float mx = -1e30f;
#pragma unroll
  for (int e = 0; e < NE; ++e) { p[e] = acc[e] + gb[e]; mx = fmaxf(mx, p[e]); }
  float s = 0.f;
#pragma unroll
  for (int e = 0; e < NE; ++e) { p[e] = expf(p[e] - mx); s += p[e]; }
  float inv = 1.f / s;
#pragma unroll
  for (int e = 0; e < NE; ++e) p[e] *= inv;

  // top-2, first-index-wins on ties (strict >)
  int e0 = 0;
#pragma unroll
  for (int e = 1; e < NE; ++e) if (p[e] > p[e0]) e0 = e;
  int e1 = (e0 == 0) ? 1 : 0;
#pragma unroll
  for (int e = 0; e < NE; ++e) if (e != e0 && p[e] > p[e1]) e1 = e;

  __shared__ float simp[4][NE];
  __shared__ float srw[4][NE];
  if (lane == 0) {
    int p0 = atomicAdd(&counts[e0], 1);
    int p1 = atomicAdd(&counts[e1], 1);
    tk_e[t * 2]     = e0;  tk_e[t * 2 + 1]   = e1;
    tk_pos[t * 2]   = p0;  tk_pos[t * 2 + 1] = p1;
    tk_w[t * 2]     = p[e0]; tk_w[t * 2 + 1] = p[e1];
#pragma unroll
    for (int e = 0; e < NE; ++e) {
      simp[wave][e] = p[e];
      srw[wave][e]  = (e == e0) ? p[e0] : ((e == e1) ? p[e1] : 0.f);
    }
  }
  __syncthreads();
  if (tid < NE) {
    float si = 0.f, sr = 0.f;
#pragma unroll
    for (int w = 0; w < 4; ++w) { si += simp[w][tid]; sr += srw[w][tid]; }
    blockImp[blockIdx.x * NE + tid] = si;
    blockRw[blockIdx.x * NE + tid]  = sr;
  }
}

// ------- gather x rows into expert-group slots (f16) --------
// writes only assignments routed to experts [g0, g0+G); Xg indexed by e-g0
__global__ __launch_bounds__(256) void gather_x(
    const float* __restrict__ x, const int* __restrict__ tk_e,
    const int* __restrict__ tk_pos, f16* __restrict__ Xg, int g0, int G) {
  const int i   = blockIdx.x;        // 0 .. N*K-1
  const int e   = tk_e[i];
  if (e < g0 || e >= g0 + G) return;
  const int pos = tk_pos[i];
  if (pos >= CAPE) return;
  const int t = i >> 1;
  const float4* src = (const float4*)(x + (size_t)t * DIM);
  f16* dst = Xg + ((size_t)((e - g0) * CAPE + pos)) * DIM;
  const int c = threadIdx.x;         // 0..255, 4 floats each
  float4 v = src[c];
  f16x4 h;
  h.x = (f16)v.x; h.y = (f16)v.y; h.z = (f16)v.z; h.w = (f16)v.w;
  *(f16x4*)(dst + c * 4) = h;
}

// ---------------- GEMM1: Hb = relu(Xg @ W1 + b1), f16 out ----------------
// Xg: (G,CAPE,DIM) f16 ; W1t: (G,HID,DIM) f16 ; Hb: (G,CAPE,HID) f16
__global__ __launch_bounds__(256) void gemm1_kernel(
    const f16* __restrict__ Xg, const f16* __restrict__ W1t,
    const float* __restrict__ b1, f16* __restrict__ Hb,
    const int* __restrict__ counts, int g0) {
  const int ez  = blockIdx.z;
  const int e   = g0 + ez;
  int cnt = counts[e]; if (cnt > CAPE) cnt = CAPE;
  const int brow = blockIdx.y;
  const int bcol = blockIdx.x;
  if (brow * 128 >= cnt) return;

  __shared__ f16 As[128 * 32];
  __shared__ f16 Bs[128 * 32];

  const int tid  = threadIdx.x;
  const int wave = tid >> 6, lane = tid & 63;
  const int wr = wave >> 1, wc = wave & 1;
  const int srow = tid >> 2;
  const int scol = (tid & 3) * 8;

  const f16* Ab = Xg  + ((size_t)ez * CAPE + brow * 128) * DIM;
  const f16* Bb = W1t + ((size_t)ez * HID  + bcol * 128) * DIM;

  f32x4 acc[4][4];
#pragma unroll
  for (int i = 0; i < 4; ++i)
#pragma unroll
    for (int j = 0; j < 4; ++j) acc[i][j] = (f32x4){0.f, 0.f, 0.f, 0.f};

  const int fr = lane & 15, fk = (lane >> 4) * 8;

  for (int kt = 0; kt < DIM / 32; ++kt) {
    const f16* Ak = Ab + kt * 32;
    const f16* Bk = Bb + kt * 32;
    gload16(Ak + (size_t)srow * DIM + scol,        As + wave * 512);
    gload16(Ak + (size_t)(srow + 64) * DIM + scol, As + 2048 + wave * 512);
    gload16(Bk + (size_t)srow * DIM + scol,        Bs + wave * 512);
    gload16(Bk + (size_t)(srow + 64) * DIM + scol, Bs + 2048 + wave * 512);
    __syncthreads();
    f16x8 af[4], bf[4];
#pragma unroll
    for (int i = 0; i < 4; ++i)
      af[i] = *(const f16x8*)&As[(wr * 64 + i * 16 + fr) * 32 + fk];
#pragma unroll
    for (int j = 0; j < 4; ++j)
      bf[j] = *(const f16x8*)&Bs[(wc * 64 + j * 16 + fr) * 32 + fk];
#pragma unroll
    for (int i = 0; i < 4; ++i)
#pragma unroll
      for (int j = 0; j < 4; ++j)
        acc[i][j] = __builtin_amdgcn_mfma_f32_16x16x32_f16(af[i], bf[j], acc[i][j], 0, 0, 0);
    __syncthreads();
  }

  const int rbase = (lane >> 4) * 4;
  const int crow0 = brow * 128 + wr * 64;
  const int ccol0 = bcol * 128 + wc * 64;
  f16* Cb = Hb + (size_t)ez * CAPE * HID;
#pragma unroll
  for (int j = 0; j < 4; ++j) {
    int col = ccol0 + j * 16 + fr;
    float bias = b1[e * HID + col];
#pragma unroll
    for (int i = 0; i < 4; ++i) {
#pragma unroll
      for (int r = 0; r < 4; ++r) {
        int row = crow0 + i * 16 + rbase + r;
        float v = acc[i][j][r] + bias;
        Cb[(size_t)row * HID + col] = (f16)(v > 0.f ? v : 0.f);
      }
    }
  }
}

// ---------------- GEMM2: Yb[e] = Hb @ W2 + b2, f16 out (no atomics) ------
// Hb: (G,CAPE,HID) f16 ; W2t: (G,OUTD,HID) f16 ; Yb: (E,CAPE,OUTD) f16
__global__ __launch_bounds__(256) void gemm2_kernel(
    const f16* __restrict__ Hb, const f16* __restrict__ W2t,
    const float* __restrict__ b2, f16* __restrict__ Yb,
    const int* __restrict__ counts, int g0) {
  const int ez  = blockIdx.z;
  const int e   = g0 + ez;
  int cnt = counts[e]; if (cnt > CAPE) cnt = CAPE;
  const int brow = blockIdx.y;
  const int bcol = blockIdx.x;
  if (brow * 128 >= cnt) return;

  __shared__ f16 As[128 * 32];
  __shared__ f16 Bs[128 * 32];

  const int tid  = threadIdx.x;
  const int wave = tid >> 6, lane = tid & 63;
  const int wr = wave >> 1, wc = wave & 1;
  const int srow = tid >> 2;
  const int scol = (tid & 3) * 8;

  const f16* Ab = Hb  + ((size_t)ez * CAPE + brow * 128) * HID;
  const f16* Bb = W2t + ((size_t)ez * OUTD + bcol * 128) * HID;

  f32x4 acc[4][4];
#pragma unroll
  for (int i = 0; i < 4; ++i)
#pragma unroll
    for (int j = 0; j < 4; ++j) acc[i][j] = (f32x4){0.f, 0.f, 0.f, 0.f};

  const int fr = lane & 15, fk = (lane >> 4) * 8;

  for (int kt = 0; kt < HID / 32; ++kt) {
    const f16* Ak = Ab + kt * 32;
    const f16* Bk = Bb + kt * 32;
    gload16(Ak + (size_t)srow * HID + scol,        As + wave * 512);
    gload16(Ak + (size_t)(srow + 64) * HID + scol, As + 2048 + wave * 512);
    gload16(Bk + (size_t)srow * HID + scol,        Bs + wave * 512);
    gload16(Bk + (size_t)(srow + 64) * HID + scol, Bs + 2048 + wave * 512);
    __syncthreads();
    f16x8 af[4], bf[4];
#pragma unroll
    for (int i = 0; i < 4; ++i)
      af[i] = *(const f16x8*)&As[(wr * 64 + i * 16 + fr) * 32 + fk];
#pragma unroll
    for (int j = 0; j < 4; ++j)
      bf[j] = *(const f16x8*)&Bs[(wc * 64 + j * 16 + fr) * 32 + fk];
#pragma unroll
    for (int i = 0; i < 4; ++i)
#pragma unroll
      for (int j = 0; j < 4; ++j)
        acc[i][j] = __builtin_amdgcn_mfma_f32_16x16x32_f16(af[i], bf[j], acc[i][j], 0, 0, 0);
    __syncthreads();
  }

  const int rbase = (lane >> 4) * 4;
  const int crow0 = brow * 128 + wr * 64;
  const int ccol0 = bcol * 128 + wc * 64;
  f16* Cb = Yb + (size_t)e * CAPE * OUTD;   // absolute expert index
#pragma unroll
  for (int j = 0; j < 4; ++j) {
    int col = ccol0 + j * 16 + fr;
    float bias = b2[e * OUTD + col];
#pragma unroll
    for (int i = 0; i < 4; ++i) {
#pragma unroll
      for (int r = 0; r < 4; ++r) {
        int row = crow0 + i * 16 + rbase + r;
        Cb[(size_t)row * OUTD + col] = (f16)(acc[i][j][r] + bias);
      }
    }
  }
}

// ---------------- combine expert outputs per token (deterministic) -------
__global__ __launch_bounds__(256) void out_gather(
    const f16* __restrict__ Yb, const int* __restrict__ tk_e,
    const int* __restrict__ tk_pos, const float* __restrict__ tk_w,
    float* __restrict__ out) {
  const int t = blockIdx.x;
  const int e0 = tk_e[t * 2],     e1 = tk_e[t * 2 + 1];
  const int p0 = tk_pos[t * 2],   p1 = tk_pos[t * 2 + 1];
  const float w0 = tk_w[t * 2],   w1 = tk_w[t * 2 + 1];
  const int c = threadIdx.x;      // 0..255, 4 elems each
  float4 r = {0.f, 0.f, 0.f, 0.f};
  if (p0 < CAPE) {
    f16x4 y = *(const f16x4*)(Yb + ((size_t)(e0 * CAPE + p0)) * OUTD + c * 4);
    r.x += w0 * (float)y.x; r.y += w0 * (float)y.y;
    r.z += w0 * (float)y.z; r.w += w0 * (float)y.w;
  }
  if (p1 < CAPE) {
    f16x4 y = *(const f16x4*)(Yb + ((size_t)(e1 * CAPE + p1)) * OUTD + c * 4);
    r.x += w1 * (float)y.x; r.y += w1 * (float)y.y;
    r.z += w1 * (float)y.z; r.w += w1 * (float)y.w;
  }
  ((float4*)(out + (size_t)t * OUTD))[c] = r;
}

// ---------------- aux loss ----------------
__global__ void aux_kernel(const float* __restrict__ blockImp,
                           const float* __restrict__ blockRw,
                           const int* __restrict__ counts,
                           float* __restrict__ out_aux) {
  const int lane = threadIdx.x;     // 64 threads
  const int e   = lane >> 3;        // 8 lanes per expert
  const int idx = lane & 7;
  double imp = 0.0, rw = 0.0;
  for (int b = idx; b < N_TOK / 4; b += 8) {
    imp += (double)blockImp[b * NE + e];
    rw  += (double)blockRw[b * NE + e];
  }
#pragma unroll
  for (int off = 1; off < 8; off <<= 1) {
    imp += __shfl_xor(imp, off);
    rw  += __shfl_xor(rw, off);
  }
  __shared__ double simp[NE], srw[NE];
  if (idx == 0) { simp[e] = imp; srw[e] = rw; }
  __syncthreads();
  if (lane == 0) {
    double mean = 0.0;
    for (int i = 0; i < NE; ++i) mean += simp[i];
    mean /= NE;
    double var = 0.0;
    for (int i = 0; i < NE; ++i) { double d = simp[i] - mean; var += d * d; }
    var /= (NE - 1);
    double il = var / (NE * NE);
    double lb = 0.0;
    for (int i = 0; i < NE; ++i)
      lb += ((double)counts[i] / N_TOK) * (srw[i] / N_TOK);
    lb *= NE;
    out_aux[0] = (float)(il + lb);
  }
}

extern "C" void kernel_launch(void* const* d_in, const int* in_sizes, int n_in,
                              void* d_out, int out_size, void* d_ws, size_t ws_size,
                              hipStream_t stream) {
  const float* x   = (const float*)d_in[0];
  const float* gW  = (const float*)d_in[1];
  const float* gb  = (const float*)d_in[2];
  const float* W1  = (const float*)d_in[3];
  const float* b1  = (const float*)d_in[4];
  const float* W2  = (const float*)d_in[5];
  const float* b2  = (const float*)d_in[6];
  float* out = (float*)d_out;

  char* ws = (char*)d_ws;
  size_t off = 0;
  // small control arrays (~0.4 MB)
  int* counts   = (int*)(ws + off); off += 256;
  int* tk_e     = (int*)(ws + off); off += (size_t)N_TOK * 2 * 4;
  int* tk_pos   = (int*)(ws + off); off += (size_t)N_TOK * 2 * 4;
  float* tk_w   = (float*)(ws + off); off += (size_t)N_TOK * 2 * 4;
  float* blockImp = (float*)(ws + off); off += (size_t)(N_TOK / 4) * NE * 4;
  float* blockRw  = (float*)(ws + off); off += (size_t)(N_TOK / 4) * NE * 4;
  off = (off + 255) & ~(size_t)255;

  // Yb always full-size (64 MB f16), persists across expert groups
  f16* Yb = (f16*)(ws + off); off += (size_t)NE * CAPE * OUTD * 2;

  // per-expert byte sizes of the group-resident buffers
  const size_t w1t_pe = (size_t)HID  * DIM * 2;   // 8 MB
  const size_t w2t_pe = (size_t)OUTD * HID * 2;   // 8 MB
  const size_t xg_pe  = (size_t)CAPE * DIM * 2;   // 8 MB
  const size_t hb_pe  = (size_t)CAPE * HID * 2;   // 32 MB
  const size_t per_e  = w1t_pe + w2t_pe + xg_pe + hb_pe;  // 56 MB

  // largest group size G (power of two) that fits
  int G = 1;
  for (int g = NE; g >= 1; g >>= 1) {
    if (off + (size_t)g * per_e <= ws_size) { G = g; break; }
  }

  f16* W1t = (f16*)(ws + off); off += (size_t)G * w1t_pe;
  f16* W2t = (f16*)(ws + off); off += (size_t)G * w2t_pe;
  f16* Xg  = (f16*)(ws + off); off += (size_t)G * xg_pe;
  f16* Hb  = (f16*)(ws + off);

  zero_ctrl<<<1, 64, 0, stream>>>(counts);

  gate_kernel<<<N_TOK / 4, 256, 0, stream>>>(x, gW, gb, counts, tk_e, tk_pos, tk_w,
                                             blockImp, blockRw);

  for (int g0 = 0; g0 < NE; g0 += G) {
    transpose_cvt<<<dim3(HID / 64, DIM / 64, G), dim3(64, 4), 0, stream>>>(
        W1, W1t, DIM, HID, g0);
    transpose_cvt<<<dim3(OUTD / 64, HID / 64, G), dim3(64, 4), 0, stream>>>(
        W2, W2t, HID, OUTD, g0);
    gather_x<<<N_TOK * 2, 256, 0, stream>>>(x, tk_e, tk_pos, Xg, g0, G);
    gemm1_kernel<<<dim3(HID / 128, CAPE / 128, G), 256, 0, stream>>>(
        Xg, W1t, b1, Hb, counts, g0);
    gemm2_kernel<<<dim3(OUTD / 128, CAPE / 128, G), 256, 0, stream>>>(
        Hb, W2t, b2, Yb, counts, g0);
  }

  out_gather<<<N_TOK, 256, 0, stream>>>(Yb, tk_e, tk_pos, tk_w, out);

  aux_kernel<<<1, 64, 0, stream>>>(blockImp, blockRw, counts, out + (size_t)N_TOK * OUTD);
}